// Round 7
// baseline (1962.401 us; speedup 1.0000x reference)
//
#include <hip/hip_runtime.h>
#include <math.h>

#define EPSv 1e-5f

typedef short short8 __attribute__((ext_vector_type(8)));
typedef float floatx4 __attribute__((ext_vector_type(4)));

__device__ __forceinline__ unsigned short f2bf(float x) {
  unsigned u = __float_as_uint(x);
  unsigned r = (u + 0x7fffu + ((u >> 16) & 1u)) >> 16;
  return (unsigned short)r;
}

// ---------------- zero the 32 stat-accumulator slots ----------------
__global__ void k_zero(float* __restrict__ p) {
  p[blockIdx.x * 256 + threadIdx.x] = 0.f;
}

// ---------------- gamma/beta for all 32 CCBNs ----------------
__global__ void k_gamma_beta(const float* __restrict__ spk, const float* __restrict__ noise,
                             const float* __restrict__ g_w, const float* __restrict__ g_b,
                             const float* __restrict__ b_w, const float* __restrict__ b_b,
                             const float* __restrict__ tl_g_w, const float* __restrict__ tl_g_b,
                             const float* __restrict__ tl_b_w, const float* __restrict__ tl_b_b,
                             float* __restrict__ gammas, float* __restrict__ betas) {
  __shared__ float condl[16*256];
  int t = threadIdx.x;
  for (int idx = t; idx < 4096; idx += 256) {
    int b = idx >> 8, k = idx & 255;
    condl[idx] = (k < 128) ? spk[b*128 + k] : noise[b*128 + k - 128];
  }
  __syncthreads();
  int i = blockIdx.x;
  const float *gw, *bw, *gbias, *bbias;
  if (i < 30) { gw = g_w + (size_t)i*65536; bw = b_w + (size_t)i*65536; gbias = g_b + i*256; bbias = b_b + i*256; }
  else { int j = i - 30; gw = tl_g_w + (size_t)j*65536; bw = tl_b_w + (size_t)j*65536; gbias = tl_g_b + j*256; bbias = tl_b_b + j*256; }
  int co = (t & 63) + blockIdx.y * 64;
  int slot = t >> 6;
  float g[4] = {0.f,0.f,0.f,0.f}, bt[4] = {0.f,0.f,0.f,0.f};
  for (int k = 0; k < 256; ++k) {
    float gwv = gw[k*256 + co];
    float bwv = bw[k*256 + co];
    #pragma unroll
    for (int bb = 0; bb < 4; ++bb) {
      float cv = condl[(slot*4 + bb)*256 + k];
      g[bb]  = fmaf(cv, gwv, g[bb]);
      bt[bb] = fmaf(cv, bwv, bt[bb]);
    }
  }
  #pragma unroll
  for (int bb = 0; bb < 4; ++bb) {
    int b = slot*4 + bb;
    gammas[i*4096 + b*256 + co] = 1.0f + g[bb] + gbias[co];
    betas [i*4096 + b*256 + co] = bt[bb] + bbias[co];
  }
}

// ---------------- weight prepack: coalesced read + coalesced uint4 writes ----------------
// dst layout per conv: [cotile(4)][chunk(8)][tap][plane(2)][co64][ci32] halves
template<int TAPS>
__device__ __forceinline__ void wprep_body(const float* __restrict__ src,
                                           unsigned short* __restrict__ dst,
                                           int cotile, int chunk, int t) {
  int cow = t >> 2, ci8 = (t & 3) * 8;
  const float* s0 = src + ((size_t)(cotile*64 + cow)*256 + chunk*32 + ci8)*TAPS;
  float v[8*TAPS];
  #pragma unroll
  for (int i = 0; i < 8*TAPS; ++i) v[i] = s0[i];   // contiguous: wave covers dense runs
  unsigned short* dblk = dst + (size_t)cotile*(8*TAPS*4096) + (size_t)chunk*(TAPS*4096);
  #pragma unroll
  for (int tap = 0; tap < TAPS; ++tap) {
    unsigned hi2[4], lo2[4];
    #pragma unroll
    for (int jj = 0; jj < 4; ++jj) {
      float a = v[(jj*2+0)*TAPS + tap], b = v[(jj*2+1)*TAPS + tap];
      unsigned short ha = f2bf(a), hb = f2bf(b);
      unsigned short la = f2bf(a - __uint_as_float((unsigned)ha << 16));
      unsigned short lb = f2bf(b - __uint_as_float((unsigned)hb << 16));
      hi2[jj] = (unsigned)ha | ((unsigned)hb << 16);
      lo2[jj] = (unsigned)la | ((unsigned)lb << 16);
    }
    uint4 H; H.x = hi2[0]; H.y = hi2[1]; H.z = hi2[2]; H.w = hi2[3];
    uint4 L; L.x = lo2[0]; L.y = lo2[1]; L.z = lo2[2]; L.w = lo2[3];
    *(uint4*)(dblk + (size_t)(tap*2)*2048 + cow*32 + ci8) = H;
    *(uint4*)(dblk + (size_t)(tap*2+1)*2048 + cow*32 + ci8) = L;
  }
}

__global__ __launch_bounds__(256) void k_wprep(const float* __restrict__ conv_w,
                                               const float* __restrict__ tl_c1_w,
                                               unsigned short* __restrict__ wp) {
  int cc = blockIdx.x;
  int cotile = blockIdx.y >> 3, chunk = blockIdx.y & 7;
  if (cc == 30) wprep_body<1>(tl_c1_w, wp + (size_t)30*655360, cotile, chunk, threadIdx.x);
  else          wprep_body<5>(conv_w + (size_t)cc*327680, wp + (size_t)cc*655360, cotile, chunk, threadIdx.x);
}

// ---------------- embedding gather + stats atomics into slot 0 ----------------
__global__ void k_embed2(const int* __restrict__ inp, const float* __restrict__ emb,
                         float* __restrict__ x, float* __restrict__ stat0) {
  int bx = blockIdx.x;            // 160 blocks x 60 rows
  int c = threadIdx.x;
  int r0 = bx * 60;
  float s = 0.f, s2 = 0.f;
  for (int r = 0; r < 60; ++r) {
    int row = inp[r0 + r];
    float v = emb[(size_t)row*256 + c];
    x[(size_t)(r0 + r)*256 + c] = v;
    s += v; s2 = fmaf(v, v, s2);
  }
  atomicAdd(&stat0[c], s);
  atomicAdd(&stat0[256 + c], s2);
}

// ---------------- MFMA dilated conv, software-pipelined ----------------
// block = 64l x 64co, 4 waves of 32l x 32co. Z double-buffered in LDS (pitch 40),
// Z globals prefetched one chunk ahead into regs, transform(c+1) overlaps MFMA(c),
// ONE barrier per chunk. W read global->reg in fragment order (L2-hot).
// R4 lesson: out-of-range rows stage EXACT ZERO (conv SAME padding).
template<int TAPS>
__global__ __launch_bounds__(256) void k_convm(const float* __restrict__ zin, float* __restrict__ out,
                        const float* __restrict__ stat_in, float* __restrict__ stat_out,
                        const float* __restrict__ gam, const float* __restrict__ bet,
                        const unsigned short* __restrict__ wpc,
                        const float* __restrict__ bias, int dil, int mode) {
  __shared__ unsigned short Zhi[2][3200];
  __shared__ unsigned short Zlo[2][3200];
  __shared__ float s_sc[256];
  __shared__ float s_sh[256];
  __shared__ float lsum[64];
  __shared__ float lsq[64];
  int t = threadIdx.x;
  int bx = blockIdx.x;
  int b  = bx / 10;
  int l0 = (bx % 10) * 64;
  int co0 = blockIdx.y * 64;
  int PAD = ((TAPS - 1)/2) * dil;
  int ROWS = 64 + 2*PAD;
  int w = t >> 6, lane = t & 63;
  int lsub = (w & 1) * 32, cosub = (w >> 1) * 32;
  int quad = lane >> 4, nlan = lane & 15;
  if (t < 64) { lsum[t] = 0.f; lsq[t] = 0.f; }
  // pre-phase: finalize BN stats, fold gamma/beta -> LDS scale/shift
  {
    float s = stat_in[t], s2 = stat_in[256 + t];
    float mu = s * (1.0f/9600.0f);
    float var = s2 * (1.0f/9600.0f) - mu*mu;
    float rs = rsqrtf(var + EPSv);
    float scale = rs * gam[b*256 + t];
    s_sc[t] = scale;
    s_sh[t] = fmaf(-mu, scale, bet[b*256 + t]);
  }

  floatx4 acc[2][2];
  #pragma unroll
  for (int i = 0; i < 2; ++i)
    #pragma unroll
    for (int j = 0; j < 2; ++j) acc[i][j] = (floatx4){0.f,0.f,0.f,0.f};

  const float* zb = zin + (size_t)b*600*256;
  int srow = t >> 3, fq = t & 7;
  int ar0 = (lsub + nlan) * 40 + quad * 8;
  int ar1 = (lsub + 16 + nlan) * 40 + quad * 8;

  // row validity (chunk-independent)
  bool va[3]; long zbase[3];
  #pragma unroll
  for (int i = 0; i < 3; ++i) {
    int r = srow + i*32;
    int gl = l0 - PAD + r;
    va[i] = (r < ROWS) && (gl >= 0) && (gl < 600);
    zbase[i] = (long)gl*256 + fq*4;
  }
  float4 pz[2][3];

  auto prefetch = [&](int chunk) {
    int set = chunk & 1;
    #pragma unroll
    for (int i = 0; i < 3; ++i) {
      float4 z = {0.f,0.f,0.f,0.f};
      if (va[i]) z = *(const float4*)&zb[zbase[i] + chunk*32];
      pz[set][i] = z;
    }
  };
  auto transform = [&](int chunk) {   // writes buf[chunk&1] from pz[chunk&1]
    int p = chunk & 1;
    int ci0 = chunk * 32;
    float4 sc4 = *(const float4*)&s_sc[ci0 + fq*4];
    float4 sh4 = *(const float4*)&s_sh[ci0 + fq*4];
    #pragma unroll
    for (int i = 0; i < 3; ++i) {
      int r = srow + i*32;
      if (r < ROWS) {
        float4 z = pz[p][i];
        bool inr = va[i];
        // SAME padding: rows outside [0,600) contribute exact zero
        float v0 = inr ? fmaxf(fmaf(z.x, sc4.x, sh4.x), 0.f) : 0.f;
        float v1 = inr ? fmaxf(fmaf(z.y, sc4.y, sh4.y), 0.f) : 0.f;
        float v2 = inr ? fmaxf(fmaf(z.z, sc4.z, sh4.z), 0.f) : 0.f;
        float v3 = inr ? fmaxf(fmaf(z.w, sc4.w, sh4.w), 0.f) : 0.f;
        unsigned short h0 = f2bf(v0), h1 = f2bf(v1), h2 = f2bf(v2), h3 = f2bf(v3);
        unsigned short e0 = f2bf(v0 - __uint_as_float((unsigned)h0 << 16));
        unsigned short e1 = f2bf(v1 - __uint_as_float((unsigned)h1 << 16));
        unsigned short e2 = f2bf(v2 - __uint_as_float((unsigned)h2 << 16));
        unsigned short e3 = f2bf(v3 - __uint_as_float((unsigned)h3 << 16));
        uint2 vh; vh.x = (unsigned)h0 | ((unsigned)h1 << 16);
        vh.y = (unsigned)h2 | ((unsigned)h3 << 16);
        uint2 vl; vl.x = (unsigned)e0 | ((unsigned)e1 << 16);
        vl.y = (unsigned)e2 | ((unsigned)e3 << 16);
        *(uint2*)&Zhi[p][r*40 + fq*4] = vh;
        *(uint2*)&Zlo[p][r*40 + fq*4] = vl;
      }
    }
  };

  prefetch(0);
  prefetch(1);
  __syncthreads();       // s_sc visible
  transform(0);          // waits pz set0 (prologue: one exposed latency)

  for (int c = 0; c < 8; ++c) {
    int p = c & 1;
    __syncthreads();     // buf[p] writes complete; prev MFMA reads complete
    // W loads for chunk c (global->reg, fragment order)
    const unsigned short* pch = wpc + (size_t)(blockIdx.y*8 + c) * (TAPS*4096);
    short8 bh[TAPS][2], bl[TAPS][2];
    #pragma unroll
    for (int tap = 0; tap < TAPS; ++tap) {
      #pragma unroll
      for (int nt = 0; nt < 2; ++nt) {
        int cw = (cosub + nt*16 + nlan)*32 + quad*8;
        bh[tap][nt] = *(const short8*)(pch + (size_t)(tap*2)*2048 + cw);
        bl[tap][nt] = *(const short8*)(pch + (size_t)(tap*2+1)*2048 + cw);
      }
    }
    if (c < 6) prefetch(c + 2);
    if (c < 7) transform(c + 1);   // VALU-heavy, covers W/prefetch latency; writes buf[p^1]
    #pragma unroll
    for (int tap = 0; tap < TAPS; ++tap) {
      int sh = tap * dil * 40;
      short8 ah0 = *(const short8*)&Zhi[p][ar0 + sh];
      short8 ah1 = *(const short8*)&Zhi[p][ar1 + sh];
      short8 al0 = *(const short8*)&Zlo[p][ar0 + sh];
      short8 al1 = *(const short8*)&Zlo[p][ar1 + sh];
      #pragma unroll
      for (int nt = 0; nt < 2; ++nt) {
        acc[0][nt] = __builtin_amdgcn_mfma_f32_16x16x32_bf16(ah0, bh[tap][nt], acc[0][nt], 0, 0, 0);
        acc[0][nt] = __builtin_amdgcn_mfma_f32_16x16x32_bf16(ah0, bl[tap][nt], acc[0][nt], 0, 0, 0);
        acc[0][nt] = __builtin_amdgcn_mfma_f32_16x16x32_bf16(al0, bh[tap][nt], acc[0][nt], 0, 0, 0);
        acc[1][nt] = __builtin_amdgcn_mfma_f32_16x16x32_bf16(ah1, bh[tap][nt], acc[1][nt], 0, 0, 0);
        acc[1][nt] = __builtin_amdgcn_mfma_f32_16x16x32_bf16(ah1, bl[tap][nt], acc[1][nt], 0, 0, 0);
        acc[1][nt] = __builtin_amdgcn_mfma_f32_16x16x32_bf16(al1, bh[tap][nt], acc[1][nt], 0, 0, 0);
      }
    }
  }

  // epilogue: bias (+residual), store, stats partials -> global atomics
  float bsv[2], ssum[2] = {0.f, 0.f}, ssq[2] = {0.f, 0.f};
  #pragma unroll
  for (int nt = 0; nt < 2; ++nt) bsv[nt] = bias[co0 + cosub + nt*16 + nlan];
  #pragma unroll
  for (int mt = 0; mt < 2; ++mt) {
    #pragma unroll
    for (int r = 0; r < 4; ++r) {
      int l = l0 + lsub + mt*16 + quad*4 + r;
      if (l < 600) {
        size_t rowo = ((size_t)(b*600 + l))*256 + co0 + cosub;
        #pragma unroll
        for (int nt = 0; nt < 2; ++nt) {
          float v = acc[mt][nt][r] + bsv[nt];
          float* dst = &out[rowo + nt*16 + nlan];
          if (mode) v += *dst;
          *dst = v;
          ssum[nt] += v;
          ssq[nt] = fmaf(v, v, ssq[nt]);
        }
      }
    }
  }
  #pragma unroll
  for (int nt = 0; nt < 2; ++nt) {
    ssum[nt] += __shfl_xor(ssum[nt], 16, 64);
    ssum[nt] += __shfl_xor(ssum[nt], 32, 64);
    ssq[nt]  += __shfl_xor(ssq[nt], 16, 64);
    ssq[nt]  += __shfl_xor(ssq[nt], 32, 64);
  }
  if (quad == 0) {
    #pragma unroll
    for (int nt = 0; nt < 2; ++nt) {
      atomicAdd(&lsum[cosub + nt*16 + nlan], ssum[nt]);
      atomicAdd(&lsq [cosub + nt*16 + nlan], ssq[nt]);
    }
  }
  __syncthreads();
  if (t < 64) {
    atomicAdd(&stat_out[co0 + t], lsum[t]);
    atomicAdd(&stat_out[256 + co0 + t], lsq[t]);
  }
}

// ---------------- token-length final 256->1 conv + relu (CCBN stats fused inline) ----------------
__global__ void k_tl2(const float* __restrict__ z, const float* __restrict__ stat,
                      const float* __restrict__ gam, const float* __restrict__ bet,
                      const float* __restrict__ w2, const float* __restrict__ b2,
                      float* __restrict__ tl) {
  int t = threadIdx.x;
  int row = blockIdx.x * 4 + (t >> 6);
  int lane = t & 63;
  int b = row / 600;
  float4 s1 = *(const float4*)&stat[lane*4];
  float4 s2 = *(const float4*)&stat[256 + lane*4];
  float4 gm = *(const float4*)&gam[b*256 + lane*4];
  float4 bt = *(const float4*)&bet[b*256 + lane*4];
  float sc[4], sh[4];
  {
    float sv[4] = {s1.x, s1.y, s1.z, s1.w};
    float qv[4] = {s2.x, s2.y, s2.z, s2.w};
    float gv[4] = {gm.x, gm.y, gm.z, gm.w};
    float bv[4] = {bt.x, bt.y, bt.z, bt.w};
    #pragma unroll
    for (int i = 0; i < 4; ++i) {
      float mu = sv[i] * (1.0f/9600.0f);
      float var = qv[i] * (1.0f/9600.0f) - mu*mu;
      float rs = rsqrtf(var + EPSv);
      sc[i] = rs * gv[i];
      sh[i] = fmaf(-mu, sc[i], bv[i]);
    }
  }
  float4 zr = *(const float4*)&z[(size_t)row*256 + lane*4];
  float4 wr = *(const float4*)&w2[lane*4];
  float z0 = fmaxf(fmaf(zr.x, sc[0], sh[0]), 0.f);
  float z1 = fmaxf(fmaf(zr.y, sc[1], sh[1]), 0.f);
  float z2 = fmaxf(fmaf(zr.z, sc[2], sh[2]), 0.f);
  float z3 = fmaxf(fmaf(zr.w, sc[3], sh[3]), 0.f);
  float s = z0*wr.x + z1*wr.y + z2*wr.z + z3*wr.w;
  for (int m = 32; m >= 1; m >>= 1) s += __shfl_xor(s, m, 64);
  if (lane == 0) tl[row] = fmaxf(s + b2[0], 0.f);
}

// ---------------- per-batch cumsum -> ends (output 1) + centers ----------------
__global__ void k_cumsum(const float* __restrict__ tl, float* __restrict__ centers,
                         float* __restrict__ out_len) {
  int b = blockIdx.x; int lane = threadIdx.x;
  float carry = 0.f;
  for (int ch = 0; ch < 10; ++ch) {
    int l = ch*64 + lane;
    float v = (l < 600) ? tl[b*600 + l] : 0.f;
    float s = v;
    #pragma unroll
    for (int off = 1; off < 64; off <<= 1) {
      float n = __shfl_up(s, off, 64);
      if (lane >= off) s += n;
    }
    float ends = carry + s;
    if (l < 600) {
      centers[b*600 + l] = ends - 0.5f*v;
      out_len[b*600 + l] = ends;
    }
    carry = __shfl(ends, 63, 64);
  }
}

// ---------------- fp32 (b,l,c) -> bf16 (b,c,l) transpose, l padded to 640 ----------------
__global__ void k_tobf16(const float* __restrict__ x, unsigned short* __restrict__ fbT) {
  __shared__ unsigned short T[64*66];
  int b = blockIdx.x, lt = blockIdx.y, ct = blockIdx.z;
  int t = threadIdx.x;
  int i4 = t >> 6;
  int j = t & 63;
  #pragma unroll
  for (int r = 0; r < 16; ++r) {
    int li = i4*16 + r;
    int l = lt*64 + li;
    float v = (l < 600) ? x[((size_t)(b*600 + l))*256 + ct*64 + j] : 0.f;
    T[j*66 + li] = f2bf(v);
  }
  __syncthreads();
  int row = t >> 2, seg = (t & 3) * 16;
  unsigned vv[8];
  #pragma unroll
  for (int k = 0; k < 8; ++k)
    vv[k] = *(const unsigned*)&T[row*66 + seg + k*2];
  size_t dsth = ((size_t)(b*256 + ct*64 + row))*640 + lt*64 + seg;
  unsigned* du = (unsigned*)fbT;
  uint4 a; a.x = vv[0]; a.y = vv[1]; a.z = vv[2]; a.w = vv[3];
  uint4 c4; c4.x = vv[4]; c4.y = vv[5]; c4.z = vv[6]; c4.w = vv[7];
  *(uint4*)(du + dsth/2) = a;
  *(uint4*)(du + dsth/2 + 4) = c4;
}

// ---------------- alignment einsum via bf16 MFMA ----------------
// phase1 = row max only; exp computed ONCE (staging threads), uint4 Wt writes
// (conflict-free), softmax denominator accumulated by staging threads.
__global__ __launch_bounds__(256) void k_align2(const unsigned short* __restrict__ fbT,
                        const float* __restrict__ centers, float* __restrict__ outp) {
  __shared__ float cen[600];
  __shared__ float mrow[64];
  __shared__ float isum[64];
  __shared__ unsigned short Wt[64*72];
  __shared__ unsigned short Ft[256*72];
  int b = blockIdx.x;
  int o0 = blockIdx.y * 64;
  int t = threadIdx.x;
  int wv = t >> 6, lane = t & 63;
  for (int i = t; i < 600; i += 256) cen[i] = centers[b*600 + i];
  __syncthreads();
  // phase 1: per-o-row max only
  for (int rr = 0; rr < 16; ++rr) {
    int oi = wv*16 + rr;
    float opos = (float)(o0 + oi);
    float mx = -3.0e38f;
    for (int l = lane; l < 600; l += 64) {
      float d = cen[l] - opos;
      mx = fmaxf(mx, -d*d*0.1f);
    }
    #pragma unroll
    for (int mm = 32; mm >= 1; mm >>= 1) mx = fmaxf(mx, __shfl_xor(mx, mm, 64));
    if (lane == 0) mrow[oi] = mx;
  }
  __syncthreads();
  floatx4 acc[4][4];
  #pragma unroll
  for (int i = 0; i < 4; ++i)
    #pragma unroll
    for (int j = 0; j < 4; ++j)
      acc[i][j] = (floatx4){0.f, 0.f, 0.f, 0.f};
  int quad = lane >> 4;
  int nlan = lane & 15;
  int oi_w = t >> 2;
  int sbase = t & 3;
  float mo = mrow[oi_w];
  float opos_w = (float)(o0 + oi_w);
  float psum = 0.f;
  const unsigned short* srcb = fbT + ((size_t)b*256)*640;

  for (int ch = 0; ch < 10; ++ch) {
    int lc0 = ch * 64;
    __syncthreads();
    // stage Wt: thread owns (row oi_w, segs sbase & sbase+4), uint4 writes
    #pragma unroll
    for (int sidx = 0; sidx < 2; ++sidx) {
      int seg = sbase + sidx*4;
      unsigned pk[4];
      #pragma unroll
      for (int jj = 0; jj < 8; jj += 2) {
        int li = lc0 + seg*8 + jj;
        float e0 = 0.f, e1 = 0.f;
        if (li < 600)     { float d = cen[li] - opos_w;     e0 = __expf(-d*d*0.1f - mo); }
        if (li + 1 < 600) { float d = cen[li + 1] - opos_w; e1 = __expf(-d*d*0.1f - mo); }
        psum += e0 + e1;
        pk[jj>>1] = (unsigned)f2bf(e0) | ((unsigned)f2bf(e1) << 16);
      }
      uint4 v; v.x = pk[0]; v.y = pk[1]; v.z = pk[2]; v.w = pk[3];
      *(uint4*)&Wt[oi_w*72 + seg*8] = v;
    }
    // stage Ft from pre-transposed bf16
    #pragma unroll
    for (int it = 0; it < 8; ++it) {
      int idx = t + it*256;
      int c = idx >> 3, part = idx & 7;
      uint4 v = *(const uint4*)(srcb + (size_t)c*640 + lc0 + part*8);
      *(uint4*)&Ft[c*72 + part*8] = v;
    }
    __syncthreads();
    #pragma unroll
    for (int ks = 0; ks < 2; ++ks) {
      int ko = ks*32 + quad*8;
      short8 af[4], bfr[4];
      #pragma unroll
      for (int mt = 0; mt < 4; ++mt)
        af[mt] = *(const short8*)&Wt[(mt*16 + nlan)*72 + ko];
      #pragma unroll
      for (int nt = 0; nt < 4; ++nt)
        bfr[nt] = *(const short8*)&Ft[(wv*64 + nt*16 + nlan)*72 + ko];
      #pragma unroll
      for (int mt = 0; mt < 4; ++mt)
        #pragma unroll
        for (int nt = 0; nt < 4; ++nt)
          acc[mt][nt] = __builtin_amdgcn_mfma_f32_16x16x32_bf16(af[mt], bfr[nt], acc[mt][nt], 0, 0, 0);
    }
  }
  // softmax denominator: reduce across the 4 staging threads per row
  psum += __shfl_xor(psum, 1, 64);
  psum += __shfl_xor(psum, 2, 64);
  if ((t & 3) == 0) isum[oi_w] = 1.0f / psum;
  __syncthreads();
  #pragma unroll
  for (int mt = 0; mt < 4; ++mt) {
    #pragma unroll
    for (int r = 0; r < 4; ++r) {
      int oi = mt*16 + quad*4 + r;
      int o = o0 + oi;
      if (o < 6000) {
        float sc = isum[oi];
        #pragma unroll
        for (int nt = 0; nt < 4; ++nt) {
          int c = wv*64 + nt*16 + nlan;
          outp[((size_t)b*6000 + o)*256 + c] = acc[mt][nt][r] * sc;
        }
      }
    }
  }
}

extern "C" void kernel_launch(void* const* d_in, const int* in_sizes, int n_in,
                              void* d_out, int out_size, void* d_ws, size_t ws_size,
                              hipStream_t stream) {
  const int*   inputs = (const int*)  d_in[0];
  const float* spk    = (const float*)d_in[1];
  const float* noise  = (const float*)d_in[2];
  const float* emb    = (const float*)d_in[3];
  const float* conv_w = (const float*)d_in[4];
  const float* conv_b = (const float*)d_in[5];
  const float* g_w    = (const float*)d_in[6];
  const float* g_b    = (const float*)d_in[7];
  const float* b_w    = (const float*)d_in[8];
  const float* b_b    = (const float*)d_in[9];
  const float* tl_g_w = (const float*)d_in[10];
  const float* tl_g_b = (const float*)d_in[11];
  const float* tl_b_w = (const float*)d_in[12];
  const float* tl_b_b = (const float*)d_in[13];
  const float* tl_c1_w = (const float*)d_in[14];
  const float* tl_c1_b = (const float*)d_in[15];
  const float* tl_c2_w = (const float*)d_in[16];
  const float* tl_c2_b = (const float*)d_in[17];
  float* out = (float*)d_out;

  float* ws = (float*)d_ws;
  float* x       = ws;                 // 2457600
  float* A       = x + 2457600;        // 2457600
  float* Bf      = A + 2457600;        // 2457600 (reused as fbT at the end)
  float* gammas  = Bf + 2457600;       // 131072
  float* betas   = gammas + 131072;    // 131072
  float* statacc = betas + 131072;     // 32 slots x 512 = 16384
  float* tl      = statacc + 16384;    // 9600
  float* cen     = tl + 9600;          // 9600
  unsigned short* wp = (unsigned short*)(cen + 9600);   // ~39.6 MB
  unsigned short* fbT = (unsigned short*)Bf;

  k_zero<<<dim3(64), dim3(256), 0, stream>>>(statacc);
  k_wprep<<<dim3(31, 32), dim3(256), 0, stream>>>(conv_w, tl_c1_w, wp);
  k_gamma_beta<<<dim3(32, 4), dim3(256), 0, stream>>>(spk, noise, g_w, g_b, b_w, b_b,
      tl_g_w, tl_g_b, tl_b_w, tl_b_b, gammas, betas);
  k_embed2<<<dim3(160), dim3(256), 0, stream>>>(inputs, emb, x, statacc);

  const int dils[3] = {1, 2, 4};
  for (int blk = 0; blk < 10; ++blk) {
    const float* srcs[3] = {x, A, Bf};
    float*       dsts[3] = {A, Bf, x};   // ping-pong; never in-place (R2 race)
    for (int j = 0; j < 3; ++j) {
      int idx = blk*3 + j;
      int mode = (j == 2) ? 1 : 0;
      k_convm<5><<<dim3(160, 4), dim3(256), 0, stream>>>(srcs[j], dsts[j],
          statacc + idx*512, statacc + (idx+1)*512,
          gammas + idx*4096, betas + idx*4096,
          wp + (size_t)idx*655360, conv_b + idx*256, dils[j], mode);
    }
  }
  // token-length head
  k_convm<1><<<dim3(160, 4), dim3(256), 0, stream>>>(x, A,
      statacc + 30*512, statacc + 31*512,
      gammas + 30*4096, betas + 30*4096,
      wp + (size_t)30*655360, tl_c1_b, 1, 0);
  k_tl2<<<dim3(2400), dim3(256), 0, stream>>>(A, statacc + 31*512,
      gammas + 31*4096, betas + 31*4096, tl_c2_w, tl_c2_b, tl);
  k_cumsum<<<dim3(16), dim3(64), 0, stream>>>(tl, cen, out + 24576000);
  // alignment einsum (bf16 MFMA)
  k_tobf16<<<dim3(16, 10, 4), dim3(256), 0, stream>>>(x, fbT);
  k_align2<<<dim3(16, 94), dim3(256), 0, stream>>>(fbT, cen, out);
}

// Round 8
// 1654.915 us; speedup vs baseline: 1.1858x; 1.1858x over previous
//
#include <hip/hip_runtime.h>
#include <math.h>

#define EPSv 1e-5f

typedef short short8 __attribute__((ext_vector_type(8)));
typedef float floatx4 __attribute__((ext_vector_type(4)));

__device__ __forceinline__ unsigned short f2bf(float x) {
  unsigned u = __float_as_uint(x);
  unsigned r = (u + 0x7fffu + ((u >> 16) & 1u)) >> 16;
  return (unsigned short)r;
}

// ---------------- zero the 32 stat-accumulator slots ----------------
__global__ void k_zero(float* __restrict__ p) {
  p[blockIdx.x * 256 + threadIdx.x] = 0.f;
}

// ---------------- gamma/beta for all 32 CCBNs ----------------
__global__ void k_gamma_beta(const float* __restrict__ spk, const float* __restrict__ noise,
                             const float* __restrict__ g_w, const float* __restrict__ g_b,
                             const float* __restrict__ b_w, const float* __restrict__ b_b,
                             const float* __restrict__ tl_g_w, const float* __restrict__ tl_g_b,
                             const float* __restrict__ tl_b_w, const float* __restrict__ tl_b_b,
                             float* __restrict__ gammas, float* __restrict__ betas) {
  __shared__ float condl[16*256];
  int t = threadIdx.x;
  for (int idx = t; idx < 4096; idx += 256) {
    int b = idx >> 8, k = idx & 255;
    condl[idx] = (k < 128) ? spk[b*128 + k] : noise[b*128 + k - 128];
  }
  __syncthreads();
  int i = blockIdx.x;
  const float *gw, *bw, *gbias, *bbias;
  if (i < 30) { gw = g_w + (size_t)i*65536; bw = b_w + (size_t)i*65536; gbias = g_b + i*256; bbias = b_b + i*256; }
  else { int j = i - 30; gw = tl_g_w + (size_t)j*65536; bw = tl_b_w + (size_t)j*65536; gbias = tl_g_b + j*256; bbias = tl_b_b + j*256; }
  int co = (t & 63) + blockIdx.y * 64;
  int slot = t >> 6;
  float g[4] = {0.f,0.f,0.f,0.f}, bt[4] = {0.f,0.f,0.f,0.f};
  for (int k = 0; k < 256; ++k) {
    float gwv = gw[k*256 + co];
    float bwv = bw[k*256 + co];
    #pragma unroll
    for (int bb = 0; bb < 4; ++bb) {
      float cv = condl[(slot*4 + bb)*256 + k];
      g[bb]  = fmaf(cv, gwv, g[bb]);
      bt[bb] = fmaf(cv, bwv, bt[bb]);
    }
  }
  #pragma unroll
  for (int bb = 0; bb < 4; ++bb) {
    int b = slot*4 + bb;
    gammas[i*4096 + b*256 + co] = 1.0f + g[bb] + gbias[co];
    betas [i*4096 + b*256 + co] = bt[bb] + bbias[co];
  }
}

// ---------------- weight prepack: coalesced read + coalesced uint4 writes ----------------
// dst layout per conv: [cotile(4)][chunk(8)][tap][plane(2)][co64][ci32] halves
template<int TAPS>
__device__ __forceinline__ void wprep_body(const float* __restrict__ src,
                                           unsigned short* __restrict__ dst,
                                           int cotile, int chunk, int t) {
  int cow = t >> 2, ci8 = (t & 3) * 8;
  const float* s0 = src + ((size_t)(cotile*64 + cow)*256 + chunk*32 + ci8)*TAPS;
  float v[8*TAPS];
  #pragma unroll
  for (int i = 0; i < 8*TAPS; ++i) v[i] = s0[i];   // contiguous: wave covers dense runs
  unsigned short* dblk = dst + (size_t)cotile*(8*TAPS*4096) + (size_t)chunk*(TAPS*4096);
  #pragma unroll
  for (int tap = 0; tap < TAPS; ++tap) {
    unsigned hi2[4], lo2[4];
    #pragma unroll
    for (int jj = 0; jj < 4; ++jj) {
      float a = v[(jj*2+0)*TAPS + tap], b = v[(jj*2+1)*TAPS + tap];
      unsigned short ha = f2bf(a), hb = f2bf(b);
      unsigned short la = f2bf(a - __uint_as_float((unsigned)ha << 16));
      unsigned short lb = f2bf(b - __uint_as_float((unsigned)hb << 16));
      hi2[jj] = (unsigned)ha | ((unsigned)hb << 16);
      lo2[jj] = (unsigned)la | ((unsigned)lb << 16);
    }
    uint4 H; H.x = hi2[0]; H.y = hi2[1]; H.z = hi2[2]; H.w = hi2[3];
    uint4 L; L.x = lo2[0]; L.y = lo2[1]; L.z = lo2[2]; L.w = lo2[3];
    *(uint4*)(dblk + (size_t)(tap*2)*2048 + cow*32 + ci8) = H;
    *(uint4*)(dblk + (size_t)(tap*2+1)*2048 + cow*32 + ci8) = L;
  }
}

__global__ __launch_bounds__(256) void k_wprep(const float* __restrict__ conv_w,
                                               const float* __restrict__ tl_c1_w,
                                               unsigned short* __restrict__ wp) {
  int cc = blockIdx.x;
  int cotile = blockIdx.y >> 3, chunk = blockIdx.y & 7;
  if (cc == 30) wprep_body<1>(tl_c1_w, wp + (size_t)30*655360, cotile, chunk, threadIdx.x);
  else          wprep_body<5>(conv_w + (size_t)cc*327680, wp + (size_t)cc*655360, cotile, chunk, threadIdx.x);
}

// ---------------- embedding gather + stats atomics into slot 0 ----------------
__global__ void k_embed2(const int* __restrict__ inp, const float* __restrict__ emb,
                         float* __restrict__ x, float* __restrict__ stat0) {
  int bx = blockIdx.x;            // 160 blocks x 60 rows
  int c = threadIdx.x;
  int r0 = bx * 60;
  float s = 0.f, s2 = 0.f;
  for (int r = 0; r < 60; ++r) {
    int row = inp[r0 + r];
    float v = emb[(size_t)row*256 + c];
    x[(size_t)(r0 + r)*256 + c] = v;
    s += v; s2 = fmaf(v, v, s2);
  }
  atomicAdd(&stat0[c], s);
  atomicAdd(&stat0[256 + c], s2);
}

// ---------------- MFMA dilated conv (R6 two-barrier structure, 32-co tiles) ----------------
// block = 64l x 32co, 4 waves of 32l x 16co. grid (160,8) = 1280 blocks = 5/CU (TLP!).
// Z single-buffer LDS (pitch 40 halves), Z globals hoisted above barrier into regs.
// W global->reg in fragment order (wp layout unchanged; co32 half of each 64-co tile).
// R4 lesson: out-of-range rows stage EXACT ZERO (conv SAME padding).
// R7 lesson: dbuf/single-barrier pipelining regresses here (lgkmcnt shared rd/wr).
template<int TAPS>
__global__ __launch_bounds__(256) void k_convm(const float* __restrict__ zin, float* __restrict__ out,
                        const float* __restrict__ stat_in, float* __restrict__ stat_out,
                        const float* __restrict__ gam, const float* __restrict__ bet,
                        const unsigned short* __restrict__ wpc,
                        const float* __restrict__ bias, int dil, int mode) {
  __shared__ unsigned short Zhi[3200];
  __shared__ unsigned short Zlo[3200];
  __shared__ float s_sc[256];
  __shared__ float s_sh[256];
  __shared__ float lsum[32];
  __shared__ float lsq[32];
  int t = threadIdx.x;
  int bx = blockIdx.x;
  int b  = bx / 10;
  int l0 = (bx % 10) * 64;
  int co0 = blockIdx.y * 32;
  int cobase = (blockIdx.y & 1) * 32;      // co offset within the 64-co wp tile
  int PAD = ((TAPS - 1)/2) * dil;
  int ROWS = 64 + 2*PAD;
  int w = t >> 6, lane = t & 63;
  int lsub = (w & 1) * 32, cosub = (w >> 1) * 16;
  int quad = lane >> 4, nlan = lane & 15;
  if (t < 32) { lsum[t] = 0.f; lsq[t] = 0.f; }
  // pre-phase: finalize BN stats, fold gamma/beta -> LDS scale/shift
  {
    float s = stat_in[t], s2 = stat_in[256 + t];
    float mu = s * (1.0f/9600.0f);
    float var = s2 * (1.0f/9600.0f) - mu*mu;
    float rs = rsqrtf(var + EPSv);
    float scale = rs * gam[b*256 + t];
    s_sc[t] = scale;
    s_sh[t] = fmaf(-mu, scale, bet[b*256 + t]);
  }

  floatx4 acc[2];
  acc[0] = (floatx4){0.f,0.f,0.f,0.f};
  acc[1] = (floatx4){0.f,0.f,0.f,0.f};

  const float* zb = zin + (size_t)b*600*256;
  int srow = t >> 3, fq = t & 7;
  int ar0 = (lsub + nlan) * 40 + quad * 8;
  int ar1 = (lsub + 16 + nlan) * 40 + quad * 8;

  // row validity (chunk-independent)
  bool va[3]; long zbase[3];
  #pragma unroll
  for (int i = 0; i < 3; ++i) {
    int r = srow + i*32;
    int gl = l0 - PAD + r;
    va[i] = (r < ROWS) && (gl >= 0) && (gl < 600);
    zbase[i] = (long)gl*256 + fq*4;
  }

  for (int chunk = 0; chunk < 8; ++chunk) {
    int ci0 = chunk * 32;
    // W fragment loads for this chunk (issue early; L2-hot)
    const unsigned short* pch = wpc + (size_t)((blockIdx.y >> 1)*8 + chunk) * (TAPS*4096);
    short8 bh[TAPS], bl[TAPS];
    int cw = (cobase + cosub + nlan)*32 + quad*8;
    #pragma unroll
    for (int tap = 0; tap < TAPS; ++tap) {
      bh[tap] = *(const short8*)(pch + (size_t)(tap*2)*2048 + cw);
      bl[tap] = *(const short8*)(pch + (size_t)(tap*2+1)*2048 + cw);
    }
    // Z loads for this chunk hoisted into regs (barrier-wait covers their latency)
    float4 zr[3];
    #pragma unroll
    for (int i = 0; i < 3; ++i) {
      float4 z = {0.f,0.f,0.f,0.f};
      if (va[i]) z = *(const float4*)&zb[zbase[i] + ci0];
      zr[i] = z;
    }
    __syncthreads();   // prev chunk's A-reads done before overwrite
    float4 sc4 = *(const float4*)&s_sc[ci0 + fq*4];
    float4 sh4 = *(const float4*)&s_sh[ci0 + fq*4];
    #pragma unroll
    for (int i = 0; i < 3; ++i) {
      int r = srow + i*32;
      if (r < ROWS) {
        float4 z = zr[i];
        bool inr = va[i];
        // SAME padding: rows outside [0,600) contribute exact zero
        float v0 = inr ? fmaxf(fmaf(z.x, sc4.x, sh4.x), 0.f) : 0.f;
        float v1 = inr ? fmaxf(fmaf(z.y, sc4.y, sh4.y), 0.f) : 0.f;
        float v2 = inr ? fmaxf(fmaf(z.z, sc4.z, sh4.z), 0.f) : 0.f;
        float v3 = inr ? fmaxf(fmaf(z.w, sc4.w, sh4.w), 0.f) : 0.f;
        unsigned short h0 = f2bf(v0), h1 = f2bf(v1), h2 = f2bf(v2), h3 = f2bf(v3);
        unsigned short e0 = f2bf(v0 - __uint_as_float((unsigned)h0 << 16));
        unsigned short e1 = f2bf(v1 - __uint_as_float((unsigned)h1 << 16));
        unsigned short e2 = f2bf(v2 - __uint_as_float((unsigned)h2 << 16));
        unsigned short e3 = f2bf(v3 - __uint_as_float((unsigned)h3 << 16));
        uint2 vh; vh.x = (unsigned)h0 | ((unsigned)h1 << 16);
        vh.y = (unsigned)h2 | ((unsigned)h3 << 16);
        uint2 vl; vl.x = (unsigned)e0 | ((unsigned)e1 << 16);
        vl.y = (unsigned)e2 | ((unsigned)e3 << 16);
        *(uint2*)&Zhi[r*40 + fq*4] = vh;
        *(uint2*)&Zlo[r*40 + fq*4] = vl;
      }
    }
    __syncthreads();
    #pragma unroll
    for (int tap = 0; tap < TAPS; ++tap) {
      int sh = tap * dil * 40;
      short8 ah0 = *(const short8*)&Zhi[ar0 + sh];
      short8 ah1 = *(const short8*)&Zhi[ar1 + sh];
      short8 al0 = *(const short8*)&Zlo[ar0 + sh];
      short8 al1 = *(const short8*)&Zlo[ar1 + sh];
      acc[0] = __builtin_amdgcn_mfma_f32_16x16x32_bf16(ah0, bh[tap], acc[0], 0, 0, 0);
      acc[0] = __builtin_amdgcn_mfma_f32_16x16x32_bf16(ah0, bl[tap], acc[0], 0, 0, 0);
      acc[0] = __builtin_amdgcn_mfma_f32_16x16x32_bf16(al0, bh[tap], acc[0], 0, 0, 0);
      acc[1] = __builtin_amdgcn_mfma_f32_16x16x32_bf16(ah1, bh[tap], acc[1], 0, 0, 0);
      acc[1] = __builtin_amdgcn_mfma_f32_16x16x32_bf16(ah1, bl[tap], acc[1], 0, 0, 0);
      acc[1] = __builtin_amdgcn_mfma_f32_16x16x32_bf16(al1, bh[tap], acc[1], 0, 0, 0);
    }
  }

  // epilogue: bias (+residual), store, stats partials -> global atomics
  float bsv = bias[co0 + cosub + nlan];
  float ssum = 0.f, ssq = 0.f;
  #pragma unroll
  for (int mt = 0; mt < 2; ++mt) {
    #pragma unroll
    for (int r = 0; r < 4; ++r) {
      int l = l0 + lsub + mt*16 + quad*4 + r;
      if (l < 600) {
        float v = acc[mt][r] + bsv;
        float* dst = &out[((size_t)(b*600 + l))*256 + co0 + cosub + nlan];
        if (mode) v += *dst;
        *dst = v;
        ssum += v;
        ssq = fmaf(v, v, ssq);
      }
    }
  }
  ssum += __shfl_xor(ssum, 16, 64);
  ssum += __shfl_xor(ssum, 32, 64);
  ssq  += __shfl_xor(ssq, 16, 64);
  ssq  += __shfl_xor(ssq, 32, 64);
  if (quad == 0) {
    atomicAdd(&lsum[cosub + nlan], ssum);
    atomicAdd(&lsq [cosub + nlan], ssq);
  }
  __syncthreads();
  if (t < 32) {
    atomicAdd(&stat_out[co0 + t], lsum[t]);
    atomicAdd(&stat_out[256 + co0 + t], lsq[t]);
  }
}

// ---------------- token-length final 256->1 conv + relu (CCBN stats fused inline) ----------------
__global__ void k_tl2(const float* __restrict__ z, const float* __restrict__ stat,
                      const float* __restrict__ gam, const float* __restrict__ bet,
                      const float* __restrict__ w2, const float* __restrict__ b2,
                      float* __restrict__ tl) {
  int t = threadIdx.x;
  int row = blockIdx.x * 4 + (t >> 6);
  int lane = t & 63;
  int b = row / 600;
  float4 s1 = *(const float4*)&stat[lane*4];
  float4 s2 = *(const float4*)&stat[256 + lane*4];
  float4 gm = *(const float4*)&gam[b*256 + lane*4];
  float4 bt = *(const float4*)&bet[b*256 + lane*4];
  float sc[4], sh[4];
  {
    float sv[4] = {s1.x, s1.y, s1.z, s1.w};
    float qv[4] = {s2.x, s2.y, s2.z, s2.w};
    float gv[4] = {gm.x, gm.y, gm.z, gm.w};
    float bv[4] = {bt.x, bt.y, bt.z, bt.w};
    #pragma unroll
    for (int i = 0; i < 4; ++i) {
      float mu = sv[i] * (1.0f/9600.0f);
      float var = qv[i] * (1.0f/9600.0f) - mu*mu;
      float rs = rsqrtf(var + EPSv);
      sc[i] = rs * gv[i];
      sh[i] = fmaf(-mu, sc[i], bv[i]);
    }
  }
  float4 zr = *(const float4*)&z[(size_t)row*256 + lane*4];
  float4 wr = *(const float4*)&w2[lane*4];
  float z0 = fmaxf(fmaf(zr.x, sc[0], sh[0]), 0.f);
  float z1 = fmaxf(fmaf(zr.y, sc[1], sh[1]), 0.f);
  float z2 = fmaxf(fmaf(zr.z, sc[2], sh[2]), 0.f);
  float z3 = fmaxf(fmaf(zr.w, sc[3], sh[3]), 0.f);
  float s = z0*wr.x + z1*wr.y + z2*wr.z + z3*wr.w;
  for (int m = 32; m >= 1; m >>= 1) s += __shfl_xor(s, m, 64);
  if (lane == 0) tl[row] = fmaxf(s + b2[0], 0.f);
}

// ---------------- per-batch cumsum -> ends (output 1) + centers ----------------
__global__ void k_cumsum(const float* __restrict__ tl, float* __restrict__ centers,
                         float* __restrict__ out_len) {
  int b = blockIdx.x; int lane = threadIdx.x;
  float carry = 0.f;
  for (int ch = 0; ch < 10; ++ch) {
    int l = ch*64 + lane;
    float v = (l < 600) ? tl[b*600 + l] : 0.f;
    float s = v;
    #pragma unroll
    for (int off = 1; off < 64; off <<= 1) {
      float n = __shfl_up(s, off, 64);
      if (lane >= off) s += n;
    }
    float ends = carry + s;
    if (l < 600) {
      centers[b*600 + l] = ends - 0.5f*v;
      out_len[b*600 + l] = ends;
    }
    carry = __shfl(ends, 63, 64);
  }
}

// ---------------- fp32 (b,l,c) -> bf16 (b,c,l) transpose, l padded to 640 ----------------
__global__ void k_tobf16(const float* __restrict__ x, unsigned short* __restrict__ fbT) {
  __shared__ unsigned short T[64*66];
  int b = blockIdx.x, lt = blockIdx.y, ct = blockIdx.z;
  int t = threadIdx.x;
  int i4 = t >> 6;
  int j = t & 63;
  #pragma unroll
  for (int r = 0; r < 16; ++r) {
    int li = i4*16 + r;
    int l = lt*64 + li;
    float v = (l < 600) ? x[((size_t)(b*600 + l))*256 + ct*64 + j] : 0.f;
    T[j*66 + li] = f2bf(v);
  }
  __syncthreads();
  int row = t >> 2, seg = (t & 3) * 16;
  unsigned vv[8];
  #pragma unroll
  for (int k = 0; k < 8; ++k)
    vv[k] = *(const unsigned*)&T[row*66 + seg + k*2];
  size_t dsth = ((size_t)(b*256 + ct*64 + row))*640 + lt*64 + seg;
  unsigned* du = (unsigned*)fbT;
  uint4 a; a.x = vv[0]; a.y = vv[1]; a.z = vv[2]; a.w = vv[3];
  uint4 c4; c4.x = vv[4]; c4.y = vv[5]; c4.z = vv[6]; c4.w = vv[7];
  *(uint4*)(du + dsth/2) = a;
  *(uint4*)(du + dsth/2 + 4) = c4;
}

// ---------------- alignment einsum via bf16 MFMA ----------------
// phase1 = row max only; exp computed ONCE (staging threads), uint4 Wt writes,
// softmax denominator accumulated by staging threads.
__global__ __launch_bounds__(256) void k_align2(const unsigned short* __restrict__ fbT,
                        const float* __restrict__ centers, float* __restrict__ outp) {
  __shared__ float cen[600];
  __shared__ float mrow[64];
  __shared__ float isum[64];
  __shared__ unsigned short Wt[64*72];
  __shared__ unsigned short Ft[256*72];
  int b = blockIdx.x;
  int o0 = blockIdx.y * 64;
  int t = threadIdx.x;
  int wv = t >> 6, lane = t & 63;
  for (int i = t; i < 600; i += 256) cen[i] = centers[b*600 + i];
  __syncthreads();
  // phase 1: per-o-row max only
  for (int rr = 0; rr < 16; ++rr) {
    int oi = wv*16 + rr;
    float opos = (float)(o0 + oi);
    float mx = -3.0e38f;
    for (int l = lane; l < 600; l += 64) {
      float d = cen[l] - opos;
      mx = fmaxf(mx, -d*d*0.1f);
    }
    #pragma unroll
    for (int mm = 32; mm >= 1; mm >>= 1) mx = fmaxf(mx, __shfl_xor(mx, mm, 64));
    if (lane == 0) mrow[oi] = mx;
  }
  __syncthreads();
  floatx4 acc[4][4];
  #pragma unroll
  for (int i = 0; i < 4; ++i)
    #pragma unroll
    for (int j = 0; j < 4; ++j)
      acc[i][j] = (floatx4){0.f, 0.f, 0.f, 0.f};
  int quad = lane >> 4;
  int nlan = lane & 15;
  int oi_w = t >> 2;
  int sbase = t & 3;
  float mo = mrow[oi_w];
  float opos_w = (float)(o0 + oi_w);
  float psum = 0.f;
  const unsigned short* srcb = fbT + ((size_t)b*256)*640;

  for (int ch = 0; ch < 10; ++ch) {
    int lc0 = ch * 64;
    __syncthreads();
    // stage Wt: thread owns (row oi_w, segs sbase & sbase+4), uint4 writes
    #pragma unroll
    for (int sidx = 0; sidx < 2; ++sidx) {
      int seg = sbase + sidx*4;
      unsigned pk[4];
      #pragma unroll
      for (int jj = 0; jj < 8; jj += 2) {
        int li = lc0 + seg*8 + jj;
        float e0 = 0.f, e1 = 0.f;
        if (li < 600)     { float d = cen[li] - opos_w;     e0 = __expf(-d*d*0.1f - mo); }
        if (li + 1 < 600) { float d = cen[li + 1] - opos_w; e1 = __expf(-d*d*0.1f - mo); }
        psum += e0 + e1;
        pk[jj>>1] = (unsigned)f2bf(e0) | ((unsigned)f2bf(e1) << 16);
      }
      uint4 v; v.x = pk[0]; v.y = pk[1]; v.z = pk[2]; v.w = pk[3];
      *(uint4*)&Wt[oi_w*72 + seg*8] = v;
    }
    // stage Ft from pre-transposed bf16
    #pragma unroll
    for (int it = 0; it < 8; ++it) {
      int idx = t + it*256;
      int c = idx >> 3, part = idx & 7;
      uint4 v = *(const uint4*)(srcb + (size_t)c*640 + lc0 + part*8);
      *(uint4*)&Ft[c*72 + part*8] = v;
    }
    __syncthreads();
    #pragma unroll
    for (int ks = 0; ks < 2; ++ks) {
      int ko = ks*32 + quad*8;
      short8 af[4], bfr[4];
      #pragma unroll
      for (int mt = 0; mt < 4; ++mt)
        af[mt] = *(const short8*)&Wt[(mt*16 + nlan)*72 + ko];
      #pragma unroll
      for (int nt = 0; nt < 4; ++nt)
        bfr[nt] = *(const short8*)&Ft[(wv*64 + nt*16 + nlan)*72 + ko];
      #pragma unroll
      for (int mt = 0; mt < 4; ++mt)
        #pragma unroll
        for (int nt = 0; nt < 4; ++nt)
          acc[mt][nt] = __builtin_amdgcn_mfma_f32_16x16x32_bf16(af[mt], bfr[nt], acc[mt][nt], 0, 0, 0);
    }
  }
  // softmax denominator: reduce across the 4 staging threads per row
  psum += __shfl_xor(psum, 1, 64);
  psum += __shfl_xor(psum, 2, 64);
  if ((t & 3) == 0) isum[oi_w] = 1.0f / psum;
  __syncthreads();
  #pragma unroll
  for (int mt = 0; mt < 4; ++mt) {
    #pragma unroll
    for (int r = 0; r < 4; ++r) {
      int oi = mt*16 + quad*4 + r;
      int o = o0 + oi;
      if (o < 6000) {
        float sc = isum[oi];
        #pragma unroll
        for (int nt = 0; nt < 4; ++nt) {
          int c = wv*64 + nt*16 + nlan;
          outp[((size_t)b*6000 + o)*256 + c] = acc[mt][nt][r] * sc;
        }
      }
    }
  }
}

extern "C" void kernel_launch(void* const* d_in, const int* in_sizes, int n_in,
                              void* d_out, int out_size, void* d_ws, size_t ws_size,
                              hipStream_t stream) {
  const int*   inputs = (const int*)  d_in[0];
  const float* spk    = (const float*)d_in[1];
  const float* noise  = (const float*)d_in[2];
  const float* emb    = (const float*)d_in[3];
  const float* conv_w = (const float*)d_in[4];
  const float* conv_b = (const float*)d_in[5];
  const float* g_w    = (const float*)d_in[6];
  const float* g_b    = (const float*)d_in[7];
  const float* b_w    = (const float*)d_in[8];
  const float* b_b    = (const float*)d_in[9];
  const float* tl_g_w = (const float*)d_in[10];
  const float* tl_g_b = (const float*)d_in[11];
  const float* tl_b_w = (const float*)d_in[12];
  const float* tl_b_b = (const float*)d_in[13];
  const float* tl_c1_w = (const float*)d_in[14];
  const float* tl_c1_b = (const float*)d_in[15];
  const float* tl_c2_w = (const float*)d_in[16];
  const float* tl_c2_b = (const float*)d_in[17];
  float* out = (float*)d_out;

  float* ws = (float*)d_ws;
  float* x       = ws;                 // 2457600
  float* A       = x + 2457600;        // 2457600
  float* Bf      = A + 2457600;        // 2457600 (reused as fbT at the end)
  float* gammas  = Bf + 2457600;       // 131072
  float* betas   = gammas + 131072;    // 131072
  float* statacc = betas + 131072;     // 32 slots x 512 = 16384
  float* tl      = statacc + 16384;    // 9600
  float* cen     = tl + 9600;          // 9600
  unsigned short* wp = (unsigned short*)(cen + 9600);   // ~39.6 MB
  unsigned short* fbT = (unsigned short*)Bf;

  k_zero<<<dim3(64), dim3(256), 0, stream>>>(statacc);
  k_wprep<<<dim3(31, 32), dim3(256), 0, stream>>>(conv_w, tl_c1_w, wp);
  k_gamma_beta<<<dim3(32, 4), dim3(256), 0, stream>>>(spk, noise, g_w, g_b, b_w, b_b,
      tl_g_w, tl_g_b, tl_b_w, tl_b_b, gammas, betas);
  k_embed2<<<dim3(160), dim3(256), 0, stream>>>(inputs, emb, x, statacc);

  const int dils[3] = {1, 2, 4};
  for (int blk = 0; blk < 10; ++blk) {
    const float* srcs[3] = {x, A, Bf};
    float*       dsts[3] = {A, Bf, x};   // ping-pong; never in-place (R2 race)
    for (int j = 0; j < 3; ++j) {
      int idx = blk*3 + j;
      int mode = (j == 2) ? 1 : 0;
      k_convm<5><<<dim3(160, 8), dim3(256), 0, stream>>>(srcs[j], dsts[j],
          statacc + idx*512, statacc + (idx+1)*512,
          gammas + idx*4096, betas + idx*4096,
          wp + (size_t)idx*655360, conv_b + idx*256, dils[j], mode);
    }
  }
  // token-length head
  k_convm<1><<<dim3(160, 8), dim3(256), 0, stream>>>(x, A,
      statacc + 30*512, statacc + 31*512,
      gammas + 30*4096, betas + 30*4096,
      wp + (size_t)30*655360, tl_c1_b, 1, 0);
  k_tl2<<<dim3(2400), dim3(256), 0, stream>>>(A, statacc + 31*512,
      gammas + 31*4096, betas + 31*4096, tl_c2_w, tl_c2_b, tl);
  k_cumsum<<<dim3(16), dim3(64), 0, stream>>>(tl, cen, out + 24576000);
  // alignment einsum (bf16 MFMA)
  k_tobf16<<<dim3(16, 10, 4), dim3(256), 0, stream>>>(x, fbT);
  k_align2<<<dim3(16, 94), dim3(256), 0, stream>>>(fbT, cen, out);
}